// Round 10
// baseline (15529.561 us; speedup 1.0000x reference)
//
#include <hip/hip_runtime.h>
#include <cstdint>
#include <cstddef>

// Problem dims: B=32, T=2048, D=512, H=512, 4H=2048
#define TT 2048
#define DD 512

// ---------------------------------------------------------------------------
// Phase 1 (chunked): xp = inputs @ Wi + b, layout: xp[tl][gate 4][B 32][col 512]
// fp32 vector GEMM, 128x128x16 tiles, 8x8 per thread.  (R6's proven version)
// ---------------------------------------------------------------------------
#define BM 128
#define BN 128
#define BK 16

__global__ __launch_bounds__(256) void xproj_gemm(
    const float* __restrict__ A,    // [32*2048, 512]
    const float* __restrict__ W,    // [512, 2048]
    const float* __restrict__ bias, // [2048]
    float* __restrict__ C,          // xp chunk
    int t0, int tmask, int tlog)    // T_CH = tmask+1 = 1<<tlog
{
    __shared__ __align__(16) float As[BK][BM + 4];   // [k][m], transposed on load
    __shared__ __align__(16) float Bs[BK][BN + 4];   // [k][n]
    const int tid = threadIdx.x;
    const int nt = blockIdx.x;
    const int mt = blockIdx.y;
    const int m_base = mt * BM;
    const int n_base = nt * BN;
    const int ty = tid >> 4;
    const int tx = tid & 15;

    float acc[8][8];
#pragma unroll
    for (int i = 0; i < 8; ++i)
#pragma unroll
        for (int j = 0; j < 8; ++j) acc[i][j] = 0.f;

    for (int k0 = 0; k0 < DD; k0 += BK) {
#pragma unroll
        for (int j = 0; j < 2; ++j) {
            int idx = tid * 2 + j;             // 0..511
            int rowl = idx >> 2, q = idx & 3;  // A: 128 rows x 4 float4
            int rc = m_base + rowl;            // chunk-local row
            int rg = ((rc >> tlog) << 11) + t0 + (rc & tmask);
            float4 av = *(const float4*)(A + (size_t)rg * DD + k0 + q * 4);
            As[q * 4 + 0][rowl] = av.x;
            As[q * 4 + 1][rowl] = av.y;
            As[q * 4 + 2][rowl] = av.z;
            As[q * 4 + 3][rowl] = av.w;
            int kr = idx >> 5, nq = idx & 31;  // B: 16 rows x 32 float4
            *(float4*)&Bs[kr][nq * 4] =
                *(const float4*)(W + (size_t)(k0 + kr) * 2048 + n_base + nq * 4);
        }
        __syncthreads();
#pragma unroll
        for (int kk = 0; kk < BK; ++kk) {
            float a[8], bb[8];
            *(float4*)&a[0]  = *(const float4*)&As[kk][ty * 8];
            *(float4*)&a[4]  = *(const float4*)&As[kk][ty * 8 + 4];
            *(float4*)&bb[0] = *(const float4*)&Bs[kk][tx * 8];
            *(float4*)&bb[4] = *(const float4*)&Bs[kk][tx * 8 + 4];
#pragma unroll
            for (int i = 0; i < 8; ++i)
#pragma unroll
                for (int j = 0; j < 8; ++j)
                    acc[i][j] = fmaf(a[i], bb[j], acc[i][j]);
        }
        __syncthreads();
    }
#pragma unroll
    for (int i = 0; i < 8; ++i) {
        int m = m_base + ty * 8 + i;
        int bglob = m >> tlog, tl = m & tmask;
#pragma unroll
        for (int j = 0; j < 8; j += 4) {
            int n = n_base + tx * 8 + j;
            int gate = n >> 9, c = n & 511;
            float4 v;
            v.x = acc[i][j + 0] + bias[n + 0];
            v.y = acc[i][j + 1] + bias[n + 1];
            v.z = acc[i][j + 2] + bias[n + 2];
            v.w = acc[i][j + 3] + bias[n + 3];
            size_t addr = (((size_t)tl * 4 + gate) * 32 + bglob) * 512 + c;
            *(float4*)(C + addr) = v;
        }
    }
}

// ---------------------------------------------------------------------------
// Phase 2: persistent LSTM scan = R9 (805us proven) + three cuts:
//  (1) TWO-DEEP pipelined poll: alternate two load sets so one is always in
//      flight while the other is checked -- detect latency ~halves (the old
//      loop serialized a full ~550cy MALL load RT per re-check).
//  (2) packed v_pk_fma_f32 dot via ext_vector(2) fma, enabled by the
//      pair-transposed h staging layout hs2[pair][k][2] (batch-pairs
//      contiguous -> b128 loads deliver ready v2f operands; same 8 b128/lane;
//      FMA issue count halves). Per-chain k-accumulation order is UNCHANGED
//      -> bit-identical numerics.
//  (3) xp prefetch moved after barrier+poison (off the poll's VMEM path,
//      hidden under the dot); T_CH probed from 512 (fewer launches).
//
// Geometry (R6): 8 groups x 32 blocks x 512 threads (1 block/CU). Group g
// owns batches [4g,4g+4). Block p owns cols [16p,16p+16). Wave w owns cols
// {16p+2w,16p+2w+1}, all 4 gates, all 4 batches. Lane l owns k in
// {4l..4l+3} U {256+4l..256+4l+3}.
//
// Poison protocol (R4/R6/R9-proven): h rotates through 3 buffers; slot owner
// poisons its recycle slot after the poll (complete h_t proves all group
// blocks consumed h_{t-1}); poison lands before the h-store to that slot via
// in-order vmcnt retirement through the next poll. 0xFFFFFFFF is NaN,
// unreachable by h = o*tanh(c) in (-1,1). Soft LDS barrier (lgkmcnt-only),
// no vmcnt drain (both validated in R9).
// ---------------------------------------------------------------------------
#define NGRP 8
#define BPG  32
#define HSZ  (32 * 512)          // one h buffer (floats)
#define POISON 0xFFFFFFFFu
#define WHST 516                 // padded wh row stride (floats)

typedef float v2f __attribute__((ext_vector_type(2)));

__device__ __forceinline__ float ldg_agent_f32(const float* p) {
    return __hip_atomic_load(p, __ATOMIC_RELAXED, __HIP_MEMORY_SCOPE_AGENT);
}
__device__ __forceinline__ v2f fma2(v2f a, v2f b, v2f c) {
    return __builtin_elementwise_fma(a, b, c);
}

// DPP quad_perm lane exchange (VALU pipe; exact xor within quads)
template<int CTRL>
__device__ __forceinline__ float dppf(float x) {
    return __int_as_float(
        __builtin_amdgcn_update_dpp(0, __float_as_int(x), CTRL, 0xf, 0xf, true));
}
// quad_perm ctrl: xor1 = 0xB1; xor2 = 0x4E; xor3 = 0x1B

// soft barrier: LDS counter; orders LDS (staging) only -- VMEM stays in flight
__device__ __forceinline__ void soft_bar(unsigned* ctr, bool leader, unsigned target) {
    asm volatile("s_waitcnt lgkmcnt(0)" ::: "memory");   // my ds_writes retired
    if (leader)
        __hip_atomic_fetch_add(ctr, 1u, __ATOMIC_RELAXED, __HIP_MEMORY_SCOPE_WORKGROUP);
    while (__hip_atomic_load(ctr, __ATOMIC_RELAXED, __HIP_MEMORY_SCOPE_WORKGROUP) < target)
        __builtin_amdgcn_s_sleep(1);
    __builtin_amdgcn_sched_barrier(0);   // no hoisting of hs reads above the spin
}

// butterfly reduce step: halve the live value count across lanes differing in bit D
template<int D, int HALF>
__device__ __forceinline__ void rstep(float* p, int lane) {
    const bool hi = (lane & D) != 0;
#pragma unroll
    for (int i = 0; i < HALF; ++i) {
        float send = hi ? p[i] : p[i + HALF];
        float recv;
        if constexpr (D == 1)      recv = dppf<0xB1>(send);
        else if constexpr (D == 2) recv = dppf<0x4E>(send);
        else                       recv = __shfl_xor(send, D, 64);
        p[i] = (hi ? p[i + HALF] : p[i]) + recv;
    }
}

__global__ __launch_bounds__(512) void lstm_scan(
    const float* __restrict__ xp,   // [tl][gate 4][B 32][col 512]
    const float* __restrict__ Wh,   // [512, 2048]
    const float* __restrict__ c0,   // [32, 512]
    const float* __restrict__ h0,   // [32, 512]
    float* __restrict__ out,        // [32, 2048, 512]
    float* hbuf,                    // [3][32][512] rotating (persists)
    float* __restrict__ cbuf,       // [32][512] c-state (persists)
    int t0, int T_CH)
{
    __shared__ float wh[64 * WHST];   // [gate*16 + local_col][k]  132,096 B
    __shared__ float hs2[2 * 2048];   // [buf][pair p][k 512][e 2]  16,384 B
    __shared__ unsigned scnt;

    const int tid  = threadIdx.x;
    const int blk  = blockIdx.x;
    const int g    = blk >> 5;      // group 0..7 (4 batches each)
    const int p    = blk & 31;      // block-in-group (16 cols each)
    const int j0   = p * 16;
    const int lane = tid & 63;
    const int w    = tid >> 6;      // wave 0..7

    // lane<32 role decode: idx = bitrev5(lane) = gate*8 + cc*4 + b
    const int idx = ((lane & 1) << 4) | ((lane & 2) << 2) | (lane & 4)
                  | ((lane >> 2) & 2) | ((lane >> 4) & 1);
    const int gate = idx >> 3;
    const int cc   = (idx >> 2) & 1;
    const int bq   = idx & 3;
    const int B    = 4 * g + bq;
    const int col  = j0 + 2 * w + cc;
    const bool low = lane < 32;
    const bool act = low && ((lane & 3) == 0);   // gate==0 owner lanes

    if (tid == 0) scnt = 0u;

    // ---- h0 / creg init (issue h0 stores FIRST so peers' polls clear) ----
    float creg = 0.f;
    if (act) {
        size_t o = (size_t)B * 512 + col;
        if (t0 == 0) {
            creg = c0[o];
            float hv = h0[o];
            if (__float_as_uint(hv) == POISON) hv = __uint_as_float(0xFFFFFFFEu);
            __hip_atomic_store(hbuf + o, hv, __ATOMIC_RELAXED, __HIP_MEMORY_SCOPE_AGENT);
        } else {
            creg = cbuf[o];   // h_{t0} already in hbuf[t0%3] from prev chunk
        }
    }

    // ---- stage Wh slice into LDS (once per launch) ----
#pragma unroll
    for (int i = 0; i < 16; ++i) {
        int id = tid + i * 512;
        int q4 = id & 3, gt = (id >> 2) & 3, k = id >> 4;
        float4 v = *(const float4*)(Wh + (size_t)k * 2048 + gt * 512 + j0 + q4 * 4);
        int r0 = gt * 16 + q4 * 4;
        wh[(r0 + 0) * WHST + k] = v.x;
        wh[(r0 + 1) * WHST + k] = v.y;
        wh[(r0 + 2) * WHST + k] = v.z;
        wh[(r0 + 3) * WHST + k] = v.w;
    }

    // staging role: batch sb = w>>1, half sh = (w&1)*256, 4 slots (q*64+lane)
    const int sb = w >> 1;
    const int sh = (w & 1) * 256;
    const int sp = sb >> 1;          // pair index
    const int se = sb & 1;           // elem within pair

    // xp prefetch for tl=0
    float xr = 0.f, xn = 0.f;
    if (low) xr = xp[((size_t)gate * 32 + B) * 512 + col];

    __syncthreads();   // one-time: wh ready + scnt published

    unsigned starget = 0;

    for (int tl = 0; tl < T_CH; ++tl) {
        const int t = t0 + tl;
        const int cur = t % 3;             // read h_t
        const int nxt = (t + 1) % 3;       // write h_{t+1}
        const int rcy = (t + 2) % 3;       // poison own slot (holds dead h_{t-1})

        // ---- TWO-DEEP pipelined poll of own 4 slots of h_t: one load set is
        // always in flight while the other is checked. Data IS the signal;
        // consuming it forces in-order vmcnt retirement of ALL older VMEM
        // (prev poison, h-store, out-store, xp load). ----
        const float* hsrc = hbuf + (size_t)cur * HSZ
                          + (size_t)(4 * g + sb) * 512 + sh + lane;
        float hvv0, hvv1, hvv2, hvv3;
        {
            float a0 = ldg_agent_f32(hsrc);
            float a1 = ldg_agent_f32(hsrc + 64);
            float a2 = ldg_agent_f32(hsrc + 128);
            float a3 = ldg_agent_f32(hsrc + 192);
            for (;;) {
                float b0 = ldg_agent_f32(hsrc);
                float b1 = ldg_agent_f32(hsrc + 64);
                float b2 = ldg_agent_f32(hsrc + 128);
                float b3 = ldg_agent_f32(hsrc + 192);
                if ((__float_as_uint(a0) != POISON) & (__float_as_uint(a1) != POISON) &
                    (__float_as_uint(a2) != POISON) & (__float_as_uint(a3) != POISON)) {
                    hvv0 = a0; hvv1 = a1; hvv2 = a2; hvv3 = a3; break;
                }
                __builtin_amdgcn_s_sleep(1);
                a0 = ldg_agent_f32(hsrc);
                a1 = ldg_agent_f32(hsrc + 64);
                a2 = ldg_agent_f32(hsrc + 128);
                a3 = ldg_agent_f32(hsrc + 192);
                if ((__float_as_uint(b0) != POISON) & (__float_as_uint(b1) != POISON) &
                    (__float_as_uint(b2) != POISON) & (__float_as_uint(b3) != POISON)) {
                    hvv0 = b0; hvv1 = b1; hvv2 = b2; hvv3 = b3; break;
                }
                __builtin_amdgcn_s_sleep(1);
            }
        }
        // stage pair-transposed: hs2[buf][sp][k][se], k = sh + q*64 + lane
        {
            float* hd = hs2 + (tl & 1) * 2048 + sp * 1024 + 2 * (sh + lane) + se;
            hd[0]       = hvv0;
            hd[2 * 64]  = hvv1;
            hd[2 * 128] = hvv2;
            hd[2 * 192] = hvv3;
        }

        // soft barrier: h_t staged block-wide (lgkmcnt-only; VMEM in flight)
        starget += 8;
        soft_bar(&scnt, lane == 0, starget);

        // ---- poison recycle slot (safe: complete h_t => every group block
        // finished step t-1). Lands before our h_{t+2} store to the same slot
        // via in-order retirement through step t+1's poll. ----
        if (act)
            __hip_atomic_store(hbuf + (size_t)rcy * HSZ + (size_t)B * 512 + col,
                               __uint_as_float(POISON),
                               __ATOMIC_RELAXED, __HIP_MEMORY_SCOPE_AGENT);
        asm volatile("" ::: "memory");   // pin issue order (poison precedes stores)

        // next-step xp prefetch: issued here (off the poll path), consumed at
        // the END of step tl+1 -- hides fully under the dot + next poll.
        if (low && (tl + 1 < T_CH))
            xn = xp[((size_t)((tl + 1) * 4 + gate) * 32 + B) * 512 + col];

        // ---- packed dot: acc2[gt*4 + c2*2 + p] = {chain b=2p, chain b=2p+1}
        // k-order per chain identical to R6/R9 -> bit-identical numerics. ----
        const float* hb2 = hs2 + (tl & 1) * 2048;
        float4 hq[2][4];
#pragma unroll
        for (int pp_ = 0; pp_ < 2; ++pp_) {
            const float* hp2 = hb2 + pp_ * 1024 + 8 * lane;
            hq[pp_][0] = *(const float4*)(hp2);          // k=4l,4l+1
            hq[pp_][1] = *(const float4*)(hp2 + 4);      // k=4l+2,4l+3
            hq[pp_][2] = *(const float4*)(hp2 + 512);    // k=256+4l,+1
            hq[pp_][3] = *(const float4*)(hp2 + 516);    // k=256+4l+2,+3
        }
        v2f acc2[16];
#pragma unroll
        for (int i = 0; i < 16; ++i) acc2[i] = (v2f)(0.f);
#pragma unroll
        for (int gt = 0; gt < 4; ++gt)
#pragma unroll
            for (int c2 = 0; c2 < 2; ++c2) {
                const float* wr = wh + (size_t)(gt * 16 + 2 * w + c2) * WHST + 4 * lane;
                float4 w0 = *(const float4*)wr;
                float4 w1 = *(const float4*)(wr + 256);
#pragma unroll
                for (int pq = 0; pq < 2; ++pq) {
                    v2f a = acc2[gt * 4 + c2 * 2 + pq];
                    a = fma2((v2f){hq[pq][0].x, hq[pq][0].y}, (v2f){w0.x, w0.x}, a);
                    a = fma2((v2f){hq[pq][0].z, hq[pq][0].w}, (v2f){w0.y, w0.y}, a);
                    a = fma2((v2f){hq[pq][1].x, hq[pq][1].y}, (v2f){w0.z, w0.z}, a);
                    a = fma2((v2f){hq[pq][1].z, hq[pq][1].w}, (v2f){w0.w, w0.w}, a);
                    a = fma2((v2f){hq[pq][2].x, hq[pq][2].y}, (v2f){w1.x, w1.x}, a);
                    a = fma2((v2f){hq[pq][2].z, hq[pq][2].w}, (v2f){w1.y, w1.y}, a);
                    a = fma2((v2f){hq[pq][3].x, hq[pq][3].y}, (v2f){w1.z, w1.z}, a);
                    a = fma2((v2f){hq[pq][3].z, hq[pq][3].w}, (v2f){w1.w, w1.w}, a);
                    acc2[gt * 4 + c2 * 2 + pq] = a;
                }
            }
        // unpack: pp[gate*8 + c2*4 + b], b = 2*pq + e (pure register naming)
        float pp[32];
#pragma unroll
        for (int gt = 0; gt < 4; ++gt)
#pragma unroll
            for (int c2 = 0; c2 < 2; ++c2)
#pragma unroll
                for (int pq = 0; pq < 2; ++pq) {
                    pp[gt * 8 + c2 * 4 + 2 * pq + 0] = acc2[gt * 4 + c2 * 2 + pq].x;
                    pp[gt * 8 + c2 * 4 + 2 * pq + 1] = acc2[gt * 4 + c2 * 2 + pq].y;
                }

        // ---- butterfly: lane ends with total for idx = bitrev5(lane&31) ----
        rstep<1, 16>(pp, lane);     // DPP
        rstep<2, 8>(pp, lane);      // DPP
        rstep<4, 4>(pp, lane);
        rstep<8, 2>(pp, lane);
        rstep<16, 1>(pp, lane);
        float v0 = pp[0] + __shfl_xor(pp[0], 32, 64);

        // ---- distributed activation: each low lane applies its gate's fn ----
        float av = 0.f;
        if (low) {
            float zz = v0 + xr;
            av = (gate == 2) ? tanhf(zz) : 1.f / (1.f + expf(-zz));
        }
        // gathers (R6/R9-verified mapping), DPP: xor1->g, xor2->f, xor3->o
        float ag = dppf<0xB1>(av);
        float af = dppf<0x4E>(av);
        float ao = dppf<0x1B>(av);

        float hn = 0.f;
        if (act) {
            float cn = af * creg + av * ag;   // sf*c + si*tg
            hn = ao * tanhf(cn);
            creg = cn;
            // h-store issues immediately (no drain -- R9-validated)
            __hip_atomic_store(hbuf + (size_t)nxt * HSZ + (size_t)B * 512 + col,
                               hn, __ATOMIC_RELAXED, __HIP_MEMORY_SCOPE_AGENT);
            out[((size_t)B * TT + t) * 512 + col] = hn;   // post-critical-path
        }
        if (low) xr = xn;
    }

    // persist c for next chunk launch (plain; kernel-boundary coherence)
    if (act) cbuf[(size_t)B * 512 + col] = creg;
}

// ---------------------------------------------------------------------------
extern "C" void kernel_launch(void* const* d_in, const int* in_sizes, int n_in,
                              void* d_out, int out_size, void* d_ws, size_t ws_size,
                              hipStream_t stream) {
    const float* inputs = (const float*)d_in[0];
    // d_in[1] = input_paddings: unused (reference discards it)
    const float* c0   = (const float*)d_in[2];
    const float* h0   = (const float*)d_in[3];
    const float* Wi   = (const float*)d_in[4];
    const float* Wh   = (const float*)d_in[5];
    const float* bias = (const float*)d_in[6];
    float* out = (float*)d_out;

    // ws layout (floats): [hbuf 3*HSZ][cbuf HSZ][xp]
    float* ws_f = (float*)d_ws;
    float* hbuf = ws_f;                              // 49152 floats
    float* cbuf = ws_f + 3 * HSZ;                    // 16384 floats
    float* xp   = ws_f + 4 * HSZ;                    // offset 65536 (16B aligned)
    const size_t extras_bytes = (size_t)(4 * HSZ) * sizeof(float);

    // pick largest T-chunk (pow2, <=512) whose xp slab fits in ws
    int T_CH = 512;
    while (T_CH > 32 &&
           extras_bytes + (size_t)T_CH * 65536 * sizeof(float) > ws_size)
        T_CH >>= 1;
    int tlog = 31 - __builtin_clz((unsigned)T_CH);

    // poison all 3 h buffers (0xFF bytes -> 0xFFFFFFFF words) before t0=0;
    // the scan kernel fills buf[0] with h0 in-kernel (polling is the sync).
    hipMemsetAsync(hbuf, 0xFF, (size_t)(3 * HSZ) * sizeof(float), stream);

    for (int t0 = 0; t0 < TT; t0 += T_CH) {
        dim3 g1(2048 / BN, (32 * T_CH) / BM);
        xproj_gemm<<<g1, 256, 0, stream>>>(inputs, Wi, bias, xp, t0, T_CH - 1, tlog);

        const float* xp_c = xp;
        int t0_arg = t0, tch_arg = T_CH;
        void* args[] = { (void*)&xp_c, (void*)&Wh, (void*)&c0, (void*)&h0,
                         (void*)&out, (void*)&hbuf, (void*)&cbuf,
                         (void*)&t0_arg, (void*)&tch_arg };
        hipLaunchCooperativeKernel((const void*)lstm_scan, dim3(NGRP * BPG), dim3(512),
                                   args, 0, stream);
    }
}